// Round 6
// baseline (248.680 us; speedup 1.0000x reference)
//
#include <hip/hip_runtime.h>

// LIF neuron forward: T=8 timesteps, x shape [T*B, C, H, W] = [256,128,32,32] f32.
// Recurrence per spatial element (independent across B,C,H,W):
//   mem = beta*mem + (1-beta)*x_t ; spike = (mem >= 0.3*Vth)*Vth ;
//   mem -= spike ; out_t = spike/0.05
//
// History:
//  R1: one-shot thread per float4 column, interleaved t-loop: 87 us,
//      3.1 TB/s CU-side (half of m13's 6.29 TB/s copy ceiling), pipes idle.
//  R3: sched_barrier phases + nt stores: nt regressed to 100 us (reverted);
//      sched_barrier defeated by IR sinking.
//  R4: asm memory clobber defeated by __restrict__ alias reasoning.
//  R5: dataflow-pin asm; VGPR stayed 24, dur 87 us. CONCLUSION: per-wave MLP
//      was never the limiter -- m13's 6.29 TB/s copy is a naive grid-stride
//      loop with no MLP, carried entirely by TLP. The real difference vs m13:
//      our waves were ONE-SHOT -- each exits with 8 stores outstanding and
//      can't release its slot until vmcnt drains, so ~half of every wave's
//      lifetime is exit-drain (also explains why nt = farther completion
//      point = worse).
//  R6: grid-stride, 4 columns/thread (1024 blocks): amortize the exit drain
//      4x. Body stays the simple interleaved per-t form.
//
// Bit-exactness notes (decisions flip 0<->20, zero flips allowed):
//  - beta = f32(exp(f32(-0.05))) = 0x1.E7078Cp-1 (correctly rounded; verified
//    absmax 0.0 in R1/R3/R4/R5).
//  - mem update uses __fmul_rn/__fadd_rn to forbid FMA contraction (numpy
//    evaluates beta*mem and (1-beta)*xt as separate rn-multiplies + rn-add).
//  - (1.0f - beta) exact; Vth clamp round-trips to 1.0f; vth/0.05f == 20.0f.

#define T_STEPS 8
#define S_ELEMS (32 * 128 * 32 * 32)   // per-timestep elements = 4,194,304
#define S4 (S_ELEMS / 4)               // float4 per timestep = 1,048,576
#define BLOCK 256
#define GRID 1024                      // 4 blocks/CU resident, 16 waves/CU
#define COLS_PER_THREAD (S4 / (GRID * BLOCK))  // = 4

typedef float f32x4 __attribute__((ext_vector_type(4)));

__global__ __launch_bounds__(BLOCK) void lif_fwd_kernel(
    const f32x4* __restrict__ x, const float* __restrict__ vth_ptr,
    f32x4* __restrict__ out) {
  const int gid = blockIdx.x * BLOCK + threadIdx.x;

  // Vth clamp (no-grad): relu(Vth - 5e-4) + 5e-4, all f32 rn. (scalar path)
  const float vth_raw = vth_ptr[0];
  const float vth = __fadd_rn(fmaxf(__fsub_rn(vth_raw, 0.0005f), 0.0f), 0.0005f);
  const float thr = __fmul_rn(0.3f, vth);      // ALPHA * Vth
  const float outval = __fdiv_rn(vth, 0.05f);  // Vth / DELTA_T (== 20.0f)

  const float beta = 0x1.E7078Cp-1f;        // f32(exp(f32(-0.05)))
  const float omb = __fsub_rn(1.0f, beta);  // exact

  // Grid-stride over float4 columns: 4 columns per thread. The exit store
  // drain (one per wave) is amortized over 4 column-passes; steady-state TLP
  // (16 waves/CU) carries the BW, per m13's naive-copy evidence.
  for (int k = 0; k < COLS_PER_THREAD; ++k) {
    const int i = gid + k * (GRID * BLOCK);
    float m0 = 0.f, m1 = 0.f, m2 = 0.f, m3 = 0.f;
#pragma unroll
    for (int t = 0; t < T_STEPS; ++t) {
      const f32x4 xv = x[i + (size_t)t * S4];
      m0 = __fadd_rn(__fmul_rn(beta, m0), __fmul_rn(omb, xv.x));
      m1 = __fadd_rn(__fmul_rn(beta, m1), __fmul_rn(omb, xv.y));
      m2 = __fadd_rn(__fmul_rn(beta, m2), __fmul_rn(omb, xv.z));
      m3 = __fadd_rn(__fmul_rn(beta, m3), __fmul_rn(omb, xv.w));
      const bool s0 = (m0 >= thr), s1 = (m1 >= thr), s2 = (m2 >= thr),
                 s3 = (m3 >= thr);
      f32x4 o;
      o.x = s0 ? outval : 0.0f;
      o.y = s1 ? outval : 0.0f;
      o.z = s2 ? outval : 0.0f;
      o.w = s3 ? outval : 0.0f;
      if (s0) m0 = __fsub_rn(m0, vth);
      if (s1) m1 = __fsub_rn(m1, vth);
      if (s2) m2 = __fsub_rn(m2, vth);
      if (s3) m3 = __fsub_rn(m3, vth);
      out[i + (size_t)t * S4] = o;
    }
  }
}

extern "C" void kernel_launch(void* const* d_in, const int* in_sizes, int n_in,
                              void* d_out, int out_size, void* d_ws,
                              size_t ws_size, hipStream_t stream) {
  const f32x4* x = (const f32x4*)d_in[0];
  const float* vth = (const float*)d_in[1];
  f32x4* out = (f32x4*)d_out;
  lif_fwd_kernel<<<GRID, BLOCK, 0, stream>>>(x, vth, out);
}

// Round 7
// 234.014 us; speedup vs baseline: 1.0627x; 1.0627x over previous
//
#include <hip/hip_runtime.h>

// LIF neuron forward: T=8 timesteps, x shape [T*B, C, H, W] = [256,128,32,32] f32.
// Recurrence per spatial element (independent across B,C,H,W):
//   mem = beta*mem + (1-beta)*x_t ; spike = (mem >= 0.3*Vth)*Vth ;
//   mem -= spike ; out_t = spike/0.05
//
// History:
//  R1: 1 float4/thread, interleaved t-loop: 87 us, ~3.0 TB/s CU-side
//      (half of m13's 6.29 TB/s HBM copy), all pipes idle.
//  R3: nt stores: 100 us (reverted). sched_barrier defeated by IR sinking.
//  R4/R5: asm clobber / dataflow-pin: emitted code unchanged (VGPR 24),
//      87 us. Per-wave MLP/ordering is NOT the limiter.
//  R6: grid-stride x4 (strided, occupancy 62%->31%): 94 us. Occupancy-
//      insensitive => TLP not the limiter either. Exit-drain theory dead.
//  => Structure-invariant ~87 us points at the ACCESS PATTERN: 16 streams
//     (8 read + 8 write planes) exactly 16 MiB apart (power-of-2 aliasing in
//     L2/L3 set indexing; 16 streams vs ~16 ways = zero slack) and only 4 KB
//     touched per plane per block before a 16 MiB hop.
//  R7: double per-stream burst: 2 contiguous columns/thread (base, base+256),
//      loads issued back-to-back -> 2 KB wave burst / 8 KB block burst per
//      plane-touch. Grid 2048. Single variable: burst length.
//
// Bit-exactness notes (decisions flip 0<->20, zero flips allowed):
//  - beta = f32(exp(f32(-0.05))) = 0x1.E7078Cp-1 (correctly rounded; verified
//    absmax 0.0 in R1/R3/R4/R5/R6).
//  - mem update uses __fmul_rn/__fadd_rn to forbid FMA contraction (numpy
//    evaluates beta*mem and (1-beta)*xt as separate rn-multiplies + rn-add).
//  - (1.0f - beta) exact; Vth clamp round-trips to 1.0f; vth/0.05f == 20.0f.

#define T_STEPS 8
#define S_ELEMS (32 * 128 * 32 * 32)   // per-timestep elements = 4,194,304
#define S4 (S_ELEMS / 4)               // float4 per timestep = 1,048,576
#define BLOCK 256
#define K_COLS 2                       // contiguous columns per thread
#define GRID (S4 / (BLOCK * K_COLS))   // 2048 blocks = 8 blocks/CU

typedef float f32x4 __attribute__((ext_vector_type(4)));

__global__ __launch_bounds__(BLOCK) void lif_fwd_kernel(
    const f32x4* __restrict__ x, const float* __restrict__ vth_ptr,
    f32x4* __restrict__ out) {
  // Block covers K_COLS*BLOCK consecutive float4 per plane (8 KB contiguous).
  const int base = blockIdx.x * (BLOCK * K_COLS) + threadIdx.x;

  // Vth clamp (no-grad): relu(Vth - 5e-4) + 5e-4, all f32 rn. (scalar path)
  const float vth_raw = vth_ptr[0];
  const float vth = __fadd_rn(fmaxf(__fsub_rn(vth_raw, 0.0005f), 0.0f), 0.0005f);
  const float thr = __fmul_rn(0.3f, vth);      // ALPHA * Vth
  const float outval = __fdiv_rn(vth, 0.05f);  // Vth / DELTA_T (== 20.0f)

  const float beta = 0x1.E7078Cp-1f;        // f32(exp(f32(-0.05)))
  const float omb = __fsub_rn(1.0f, beta);  // exact

  float a0 = 0.f, a1 = 0.f, a2 = 0.f, a3 = 0.f;  // mem, column A (base)
  float b0 = 0.f, b1 = 0.f, b2 = 0.f, b3 = 0.f;  // mem, column B (base+BLOCK)

#pragma unroll
  for (int t = 0; t < T_STEPS; ++t) {
    const size_t p = (size_t)t * S4;
    // Two adjacent 1-KB wave bursts per plane, issued back-to-back.
    const f32x4 xa = x[base + p];
    const f32x4 xb = x[base + BLOCK + p];

    a0 = __fadd_rn(__fmul_rn(beta, a0), __fmul_rn(omb, xa.x));
    a1 = __fadd_rn(__fmul_rn(beta, a1), __fmul_rn(omb, xa.y));
    a2 = __fadd_rn(__fmul_rn(beta, a2), __fmul_rn(omb, xa.z));
    a3 = __fadd_rn(__fmul_rn(beta, a3), __fmul_rn(omb, xa.w));
    b0 = __fadd_rn(__fmul_rn(beta, b0), __fmul_rn(omb, xb.x));
    b1 = __fadd_rn(__fmul_rn(beta, b1), __fmul_rn(omb, xb.y));
    b2 = __fadd_rn(__fmul_rn(beta, b2), __fmul_rn(omb, xb.z));
    b3 = __fadd_rn(__fmul_rn(beta, b3), __fmul_rn(omb, xb.w));

    const bool sa0 = (a0 >= thr), sa1 = (a1 >= thr), sa2 = (a2 >= thr),
               sa3 = (a3 >= thr);
    const bool sb0 = (b0 >= thr), sb1 = (b1 >= thr), sb2 = (b2 >= thr),
               sb3 = (b3 >= thr);
    f32x4 oa, ob;
    oa.x = sa0 ? outval : 0.0f;
    oa.y = sa1 ? outval : 0.0f;
    oa.z = sa2 ? outval : 0.0f;
    oa.w = sa3 ? outval : 0.0f;
    ob.x = sb0 ? outval : 0.0f;
    ob.y = sb1 ? outval : 0.0f;
    ob.z = sb2 ? outval : 0.0f;
    ob.w = sb3 ? outval : 0.0f;
    if (sa0) a0 = __fsub_rn(a0, vth);
    if (sa1) a1 = __fsub_rn(a1, vth);
    if (sa2) a2 = __fsub_rn(a2, vth);
    if (sa3) a3 = __fsub_rn(a3, vth);
    if (sb0) b0 = __fsub_rn(b0, vth);
    if (sb1) b1 = __fsub_rn(b1, vth);
    if (sb2) b2 = __fsub_rn(b2, vth);
    if (sb3) b3 = __fsub_rn(b3, vth);

    // Two adjacent 1-KB wave store bursts, back-to-back.
    out[base + p] = oa;
    out[base + BLOCK + p] = ob;
  }
}

extern "C" void kernel_launch(void* const* d_in, const int* in_sizes, int n_in,
                              void* d_out, int out_size, void* d_ws,
                              size_t ws_size, hipStream_t stream) {
  const f32x4* x = (const f32x4*)d_in[0];
  const float* vth = (const float*)d_in[1];
  f32x4* out = (f32x4*)d_out;
  lif_fwd_kernel<<<GRID, BLOCK, 0, stream>>>(x, vth, out);
}

// Round 8
// 230.112 us; speedup vs baseline: 1.0807x; 1.0170x over previous
//
#include <hip/hip_runtime.h>

// LIF neuron forward: T=8 timesteps, x shape [T*B, C, H, W] = [256,128,32,32] f32.
// Recurrence per spatial element (independent across B,C,H,W):
//   mem = beta*mem + (1-beta)*x_t ; spike = (mem >= 0.3*Vth)*Vth ;
//   mem -= spike ; out_t = spike/0.05
//
// History:
//  R1: 1 float4/thread one-shot: 87 us, ~3.0 TB/s CU-side (vs m13 copy 6.29,
//      and harness fillBuffer measured at 6.55 TB/s in-process). Pipes idle.
//  R3: nt stores: 100 us (reverted). R4/R5: asm pins defeated/no effect --
//      per-wave MLP/ordering not the limiter.
//  R6: grid-stride x4, occupancy 62->31%: 94 us. Occupancy-insensitive.
//  R7: 2 contiguous cols/thread (8 KB/block/plane bursts): 82 us (-6%).
//      Burst length is the only variable that has moved the needle.
//  R8: K_COLS=8 interleaved cols/thread -> 8 coalesced 1-KB load insts
//      back-to-back = 32 KB contiguous per block per plane-touch (and 8 KB
//      of reads in flight per wave). Grid 512. Single variable: burst x4.
//
// Bit-exactness notes (decisions flip 0<->20, zero flips allowed):
//  - beta = f32(exp(f32(-0.05))) = 0x1.E7078Cp-1 (correctly rounded; verified
//    absmax 0.0 in R1/R3/R4/R5/R6/R7).
//  - mem update uses __fmul_rn/__fadd_rn to forbid FMA contraction (numpy
//    evaluates beta*mem and (1-beta)*xt as separate rn-multiplies + rn-add).
//  - (1.0f - beta) exact; Vth clamp round-trips to 1.0f; vth/0.05f == 20.0f.

#define T_STEPS 8
#define S_ELEMS (32 * 128 * 32 * 32)   // per-timestep elements = 4,194,304
#define S4 (S_ELEMS / 4)               // float4 per timestep = 1,048,576
#define BLOCK 256
#define K_COLS 8                       // interleaved columns per thread
#define GRID (S4 / (BLOCK * K_COLS))   // 512 blocks = 2 blocks/CU

typedef float f32x4 __attribute__((ext_vector_type(4)));

__global__ __launch_bounds__(BLOCK) void lif_fwd_kernel(
    const f32x4* __restrict__ x, const float* __restrict__ vth_ptr,
    f32x4* __restrict__ out) {
  // Block covers BLOCK*K_COLS consecutive float4 per plane (32 KB contiguous);
  // thread handles columns base + k*BLOCK so every load inst is a fully
  // coalesced 1-KB wave access.
  const int base = blockIdx.x * (BLOCK * K_COLS) + threadIdx.x;

  // Vth clamp (no-grad): relu(Vth - 5e-4) + 5e-4, all f32 rn. (scalar path)
  const float vth_raw = vth_ptr[0];
  const float vth = __fadd_rn(fmaxf(__fsub_rn(vth_raw, 0.0005f), 0.0f), 0.0005f);
  const float thr = __fmul_rn(0.3f, vth);      // ALPHA * Vth
  const float outval = __fdiv_rn(vth, 0.05f);  // Vth / DELTA_T (== 20.0f)

  const float beta = 0x1.E7078Cp-1f;        // f32(exp(f32(-0.05)))
  const float omb = __fsub_rn(1.0f, beta);  // exact

  float m[K_COLS * 4];
#pragma unroll
  for (int j = 0; j < K_COLS * 4; ++j) m[j] = 0.0f;

#pragma unroll
  for (int t = 0; t < T_STEPS; ++t) {
    const size_t p = (size_t)t * S4;

    // 8 back-to-back coalesced 1-KB loads: 32 KB contiguous block burst.
    f32x4 xv[K_COLS];
#pragma unroll
    for (int k = 0; k < K_COLS; ++k) xv[k] = x[base + k * BLOCK + p];

#pragma unroll
    for (int k = 0; k < K_COLS; ++k) {
      f32x4 o;
#pragma unroll
      for (int c = 0; c < 4; ++c) {
        const float mm =
            __fadd_rn(__fmul_rn(beta, m[k * 4 + c]), __fmul_rn(omb, xv[k][c]));
        const bool s = (mm >= thr);
        o[c] = s ? outval : 0.0f;
        m[k * 4 + c] = s ? __fsub_rn(mm, vth) : mm;
      }
      // 8 back-to-back coalesced 1-KB stores: 32 KB contiguous block burst.
      out[base + k * BLOCK + p] = o;
    }
  }
}

extern "C" void kernel_launch(void* const* d_in, const int* in_sizes, int n_in,
                              void* d_out, int out_size, void* d_ws,
                              size_t ws_size, hipStream_t stream) {
  const f32x4* x = (const f32x4*)d_in[0];
  const float* vth = (const float*)d_in[1];
  f32x4* out = (f32x4*)d_out;
  lif_fwd_kernel<<<GRID, BLOCK, 0, stream>>>(x, vth, out);
}